// Round 1
// 861.494 us; speedup vs baseline: 1.0396x; 1.0396x over previous
//
#include <hip/hip_runtime.h>
#include <math.h>

// ArcFace margin loss: B=1024 x E=512 embeddings vs C=200000 x E weight.
// Round 5: (1) double-buffered LDS with prefetch-before-compute (T3 minimum
// 2-phase: STAGE(k+1) issued before ds_read+MFMA of k, one barrier/K-step);
// (2) bijective XCD-aware block remap so the 4 row-tiles sharing a W chunk
// run on the same XCD (B becomes L2-hit, fetch ~halves);
// (3) T2-style XOR slot swizzle (both-sides: pre-swizzled global source +
// swizzled read slot; LDS dest linear for global_load_lds) to kill the
// 8-way bank conflict on ds_read_b128 of the 64B-stride tiles.

#define S_SCALE 64.0f
#define MARGIN2 0.5f
#define EPSS 1e-7f

#define BATCH 1024
#define EMB 512
#define NCLS 200000

#define BM 256
#define BN 128
#define BK 32
#define NCHUNKS ((NCLS + BN - 1) / BN) // 1563
#define NCLS_PAD (NCHUNKS * BN)        // 200064
#define NBLK (4 * NCHUNKS)             // 6252 total blocks

typedef __bf16 bf16x8 __attribute__((ext_vector_type(8)));
typedef float floatx4 __attribute__((ext_vector_type(4)));

// ---- workspace layout (float offsets) ----
#define OFF_NEBF 0
#define LEN_NEBF (BATCH * EMB / 2)           // 262144 floats
#define OFF_WINV (OFF_NEBF + LEN_NEBF)       // fallback path only
#define LEN_WINV 200192
#define OFF_PL (OFF_WINV + LEN_WINV)
#define LEN_P (BATCH * NCHUNKS)              // 1600512
#define OFF_TSV (OFF_PL + LEN_P)
#define OFF_RL (OFF_TSV + BATCH)
#define OFF_WBF (OFF_RL + BATCH)             // ~8.3 MB so far
#define LEN_WBF ((size_t)NCLS_PAD * EMB / 2) // ~205 MB
#define NEED_BYTES (((size_t)OFF_WBF + LEN_WBF) * 4)

__device__ inline ushort f2bf(float f) {
    unsigned u = __float_as_uint(f);
    unsigned r = (u + 0x7FFFu + ((u >> 16) & 1u)) >> 16; // RNE
    return (ushort)r;
}

// async global->LDS, 16 B per lane; LDS dest = wave-uniform base + lane*16.
__device__ __forceinline__ void gload_lds16(const void* g, void* l) {
    __builtin_amdgcn_global_load_lds(
        (const __attribute__((address_space(1))) void*)g,
        (__attribute__((address_space(3))) void*)l, 16, 0, 0);
}

// Kernel 1: L2-normalize embedding rows -> bf16. One block per row.
__global__ void norm_emb_kernel(const float* __restrict__ e, ushort* __restrict__ nebf) {
    int r = blockIdx.x;
    int t = threadIdx.x;
    float v0 = e[r * EMB + t];
    float v1 = e[r * EMB + t + 256];
    __shared__ float red[256];
    red[t] = v0 * v0 + v1 * v1;
    __syncthreads();
    for (int o = 128; o > 0; o >>= 1) {
        if (t < o) red[t] += red[t + o];
        __syncthreads();
    }
    float inv = 1.0f / fmaxf(sqrtf(red[0]), 1e-12f);
    nebf[r * EMB + t] = f2bf(v0 * inv);
    nebf[r * EMB + t + 256] = f2bf(v1 * inv);
}

// Kernel 2a (PRE path): per-class normalize + fp32->bf16 convert, one wave/row.
__global__ void norm_w_kernel(const float* __restrict__ w, ushort* __restrict__ wbf) {
    int tid = threadIdx.x;
    int wv = tid >> 6, lane = tid & 63;
    int row = blockIdx.x * 4 + wv; // grid = 50000 -> exactly 200000 rows
    const float* wr = w + (size_t)row * EMB;
    float4 v0 = *(const float4*)(wr + lane * 4);
    float4 v1 = *(const float4*)(wr + lane * 4 + 256);
    float ss = v0.x * v0.x + v0.y * v0.y + v0.z * v0.z + v0.w * v0.w
             + v1.x * v1.x + v1.y * v1.y + v1.z * v1.z + v1.w * v1.w;
#pragma unroll
    for (int m = 32; m >= 1; m >>= 1) ss += __shfl_xor(ss, m);
    float inv = 1.0f / fmaxf(sqrtf(ss), 1e-12f);
    ushort* dst = wbf + (size_t)row * EMB;
    ushort4 p0, p1;
    p0.x = f2bf(v0.x * inv); p0.y = f2bf(v0.y * inv);
    p0.z = f2bf(v0.z * inv); p0.w = f2bf(v0.w * inv);
    p1.x = f2bf(v1.x * inv); p1.y = f2bf(v1.y * inv);
    p1.z = f2bf(v1.z * inv); p1.w = f2bf(v1.w * inv);
    *(ushort4*)(dst + lane * 4) = p0;
    *(ushort4*)(dst + lane * 4 + 256) = p1;
}

// Kernel 2b (fallback): per-class inverse norms only.
__global__ void winv_kernel(const float* __restrict__ w, float* __restrict__ winv) {
    int tid = threadIdx.x;
    int wv = tid >> 6, lane = tid & 63;
    int row = blockIdx.x * 4 + wv;
    const float* wr = w + (size_t)row * EMB;
    float ss = 0.f;
#pragma unroll
    for (int q = 0; q < 8; ++q) {
        float v = wr[lane + 64 * q];
        ss += v * v;
    }
#pragma unroll
    for (int m = 32; m >= 1; m >>= 1) ss += __shfl_xor(ss, m);
    if (lane == 0) winv[row] = 1.0f / fmaxf(sqrtf(ss), 1e-12f);
}

// Kernel 3: bf16 MFMA GEMM + fused arcface epilogue (fixed max = 64).
// Block = 512 threads = 8 waves (wave_m 0..3, wave_n 0..1), each wave 64x64.
// LDS tiles double-buffered, row stride 32 bf16 = 64 B; 16B slots XOR-swizzled.
template <bool PRE>
__global__ __launch_bounds__(512) void gemm_lse_kernel(
    const ushort* __restrict__ nebf, const ushort* __restrict__ wbf,
    const float* __restrict__ w, const float* __restrict__ winv,
    const int* __restrict__ labels,
    float* __restrict__ pl, float* __restrict__ tsv) {
    __shared__ ushort Als[2][BM * 32];  // 2 x 16 KB
    __shared__ ushort Bls[2][BN * 32];  // 2 x 8 KB
    __shared__ float psum[2][BM];       // 2 KB  (total 50 KB -> 3 blocks/CU)

    const int tid = threadIdx.x;

    // ---- bijective XCD remap (m204): dispatch-linear d -> logical tile so
    // each XCD owns a contiguous logical range; the 4 row-tiles of a W chunk
    // are logically consecutive -> same XCD -> B chunk is fetched once.
    const int d = blockIdx.y * 4 + blockIdx.x; // dispatch order, x fastest
    const int xcd = d & 7, slot = d >> 3;
    const int qq = NBLK >> 3, rr = NBLK & 7;   // 781, 4
    const int logical =
        ((xcd < rr) ? xcd * (qq + 1) : rr * (qq + 1) + (xcd - rr) * qq) + slot;
    const int rowBase = (logical & 3) * BM;
    const int chunk = logical >> 2;            // 0..1562
    const int colBase = chunk * BN;

    const int lane = tid & 63, wv = tid >> 6;
    const int wave_m = wv & 3, wave_n = wv >> 2;
    const int lr = lane & 15, quad = lane >> 4;

    // staging lane mapping: 1 KB segment = 16 rows x 64 B; lane l -> row l/4.
    // T2 slot swizzle: physical slot p at row r holds logical slot p^((r>>1)&3).
    // global_load_lds writes physical slot (lane&3) linearly, so the SOURCE is
    // pre-swizzled; reads apply the same XOR. (r>>1)&3 == (srow>>1)&3 for all
    // segment bases used here (multiples of 16/32).
    const int srow = lane >> 2;
    const int skoff = (((lane & 3) ^ ((srow >> 1) & 3)) * 8);
    const int rq = (quad ^ ((lr >> 1) & 3)) * 8; // swizzled read slot (ushorts)

    // fallback manual B staging indices
    const int bcol = tid >> 2, bq = tid & 3;
    const int bslot = ((bq ^ ((bcol >> 1) & 3)) * 8);
    const int bcls = colBase + bcol;
    const bool bvalid = bcls < NCLS;

    floatx4 acc[4][4];
#pragma unroll
    for (int i = 0; i < 4; i++)
#pragma unroll
        for (int j = 0; j < 4; j++) acc[i][j] = (floatx4){0.f, 0.f, 0.f, 0.f};

    // per-wave staging source pointers (advance by BK each K-step)
    const ushort* aseg0 = nebf + (size_t)(rowBase + wv * 32 + srow) * EMB + skoff;
    const ushort* aseg1 = aseg0 + (size_t)16 * EMB;
    const ushort* bseg = PRE ? (wbf + (size_t)(colBase + wv * 16 + srow) * EMB + skoff) : (const ushort*)0;

#define STAGE_A(b, kt)                                                 \
    do {                                                               \
        gload_lds16(aseg0 + (kt), &Als[b][(wv * 32) * 32]);            \
        gload_lds16(aseg1 + (kt), &Als[b][(wv * 32 + 16) * 32]);       \
    } while (0)
#define STAGE_B(b, kt) gload_lds16(bseg + (kt), &Bls[b][(wv * 16) * 32])
#define COMPUTE(b)                                                                    \
    do {                                                                              \
        bf16x8 af[4], bfr[4];                                                         \
        _Pragma("unroll") for (int i = 0; i < 4; i++)                                 \
            af[i] = *(const bf16x8*)&Als[b][(wave_m * 64 + i * 16 + lr) * 32 + rq];   \
        _Pragma("unroll") for (int j = 0; j < 4; j++)                                 \
            bfr[j] = *(const bf16x8*)&Bls[b][(wave_n * 64 + j * 16 + lr) * 32 + rq];  \
        _Pragma("unroll") for (int i = 0; i < 4; i++)                                 \
            _Pragma("unroll") for (int j = 0; j < 4; j++)                             \
                acc[i][j] = __builtin_amdgcn_mfma_f32_16x16x32_bf16(af[i], bfr[j],    \
                                                                    acc[i][j], 0, 0, 0); \
    } while (0)

    if (PRE) {
        // prologue: stage tile 0 into buf 0; barrier drains vmcnt
        STAGE_A(0, 0);
        STAGE_B(0, 0);
        __syncthreads();
        int cur = 0;
#pragma unroll
        for (int kt = BK; kt < EMB; kt += BK) {
            STAGE_A(cur ^ 1, kt);   // issue next-tile loads FIRST (hide latency
            STAGE_B(cur ^ 1, kt);   // under current-tile ds_read + MFMA)
            COMPUTE(cur);
            __syncthreads();        // drains vmcnt(0)+lgkmcnt(0): buf cur^1 ready
            cur ^= 1;
        }
        COMPUTE(cur);
    } else {
        // fallback: A via gload_lds; B fp32->bf16 reg-staged with same dbuf.
        {
            STAGE_A(0, 0);
            float4 v0 = make_float4(0.f, 0.f, 0.f, 0.f);
            float4 v1 = make_float4(0.f, 0.f, 0.f, 0.f);
            if (bvalid) {
                const float* src = w + (size_t)bcls * EMB + bq * 8;
                v0 = *(const float4*)(src);
                v1 = *(const float4*)(src + 4);
            }
            union { ushort us[8]; uint4 v; } pk;
            pk.us[0] = f2bf(v0.x); pk.us[1] = f2bf(v0.y);
            pk.us[2] = f2bf(v0.z); pk.us[3] = f2bf(v0.w);
            pk.us[4] = f2bf(v1.x); pk.us[5] = f2bf(v1.y);
            pk.us[6] = f2bf(v1.z); pk.us[7] = f2bf(v1.w);
            *(uint4*)&Bls[0][bcol * 32 + bslot] = pk.v;
            __syncthreads();
        }
        int cur = 0;
#pragma unroll
        for (int kt = BK; kt < EMB; kt += BK) {
            STAGE_A(cur ^ 1, kt);
            float4 v0 = make_float4(0.f, 0.f, 0.f, 0.f);
            float4 v1 = make_float4(0.f, 0.f, 0.f, 0.f);
            if (bvalid) {
                const float* src = w + (size_t)bcls * EMB + kt + bq * 8;
                v0 = *(const float4*)(src);
                v1 = *(const float4*)(src + 4);
            }
            COMPUTE(cur);
            union { ushort us[8]; uint4 v; } pk;
            pk.us[0] = f2bf(v0.x); pk.us[1] = f2bf(v0.y);
            pk.us[2] = f2bf(v0.z); pk.us[3] = f2bf(v0.w);
            pk.us[4] = f2bf(v1.x); pk.us[5] = f2bf(v1.y);
            pk.us[6] = f2bf(v1.z); pk.us[7] = f2bf(v1.w);
            *(uint4*)&Bls[cur ^ 1][bcol * 32 + bslot] = pk.v;
            __syncthreads();
            cur ^= 1;
        }
        COMPUTE(cur);
    }
#undef STAGE_A
#undef STAGE_B
#undef COMPUTE

    // ---- epilogue: contribution = exp(64*cos - 64); max statically = 64 ----
    float wvv[4];
    if (!PRE) {
#pragma unroll
        for (int j = 0; j < 4; j++) {
            int gc = colBase + wave_n * 64 + j * 16 + lr;
            wvv[j] = (gc < NCLS) ? winv[gc] : 0.f;
        }
    }
#pragma unroll
    for (int i = 0; i < 4; i++) {
#pragma unroll
        for (int r = 0; r < 4; r++) {
            int rowloc = wave_m * 64 + i * 16 + quad * 4 + r;
            int grow = rowBase + rowloc;
            int lbl = labels[grow];
            float s = 0.f;
#pragma unroll
            for (int j = 0; j < 4; j++) {
                int gc = colBase + wave_n * 64 + j * 16 + lr;
                if (gc < NCLS) {
                    float c = PRE ? acc[i][j][r] : acc[i][j][r] * wvv[j];
                    c = fminf(fmaxf(c, -1.f), 1.f);
                    if (gc == lbl) {
                        float tt = fminf(fmaxf(c, -1.f + EPSS), 1.f - EPSS);
                        c = __cosf(acosf(tt) + MARGIN2);
                        tsv[grow] = c * S_SCALE; // unique writer across grid
                    }
                    s += __expf(c * S_SCALE - S_SCALE);
                }
            }
#pragma unroll
            for (int m = 1; m < 16; m <<= 1) s += __shfl_xor(s, m);
            if (lr == 0) psum[wave_n][rowloc] = s;
        }
    }
    __syncthreads();
    if (tid < BM) {
        size_t grow = rowBase + tid;
        pl[grow * NCHUNKS + chunk] = psum[0][tid] + psum[1][tid];
    }
}

// Kernel 4: per-row sum over chunk partials -> row loss (max fixed at 64).
__global__ void chunk_reduce_kernel(const float* __restrict__ pl,
                                    const float* __restrict__ tsv, float* __restrict__ rowloss) {
    int r = blockIdx.x, t = threadIdx.x;
    const float* l = pl + (size_t)r * NCHUNKS;
    __shared__ float red[256];
    float s = 0.f;
    for (int i = t; i < NCHUNKS; i += 256) s += l[i];
    red[t] = s;
    __syncthreads();
    for (int o = 128; o > 0; o >>= 1) {
        if (t < o) red[t] += red[t + o];
        __syncthreads();
    }
    if (t == 0) rowloss[r] = S_SCALE + logf(red[0]) - tsv[r];
}

// Kernel 5: mean over rows -> scalar loss.
__global__ void final_kernel(const float* __restrict__ rowloss, float* __restrict__ out) {
    int t = threadIdx.x;
    float s = 0.f;
    for (int i = t; i < BATCH; i += 256) s += rowloss[i];
    __shared__ float red[256];
    red[t] = s;
    __syncthreads();
    for (int o = 128; o > 0; o >>= 1) {
        if (t < o) red[t] += red[t + o];
        __syncthreads();
    }
    if (t == 0) out[0] = red[0] / (float)BATCH;
}

extern "C" void kernel_launch(void* const* d_in, const int* in_sizes, int n_in,
                              void* d_out, int out_size, void* d_ws, size_t ws_size,
                              hipStream_t stream) {
    const float* emb = (const float*)d_in[0];
    const float* w = (const float*)d_in[1];
    const int* labels = (const int*)d_in[2];
    float* ws = (float*)d_ws;
    ushort* nebf = (ushort*)(ws + OFF_NEBF);
    float* winv = ws + OFF_WINV;
    float* pl = ws + OFF_PL;
    float* tsv = ws + OFF_TSV;
    float* rl = ws + OFF_RL;
    ushort* wbf = (ushort*)(ws + OFF_WBF);

    const bool pre = ws_size >= NEED_BYTES;

    norm_emb_kernel<<<BATCH, 256, 0, stream>>>(emb, nebf);
    dim3 grid(BATCH / BM, NCHUNKS); // remapped in-kernel (XCD-bijective)
    if (pre) {
        norm_w_kernel<<<NCLS / 4, 256, 0, stream>>>(w, wbf);
        gemm_lse_kernel<true><<<grid, 512, 0, stream>>>(nebf, wbf, w, winv, labels, pl, tsv);
    } else {
        winv_kernel<<<NCLS / 4, 256, 0, stream>>>(w, winv);
        gemm_lse_kernel<false><<<grid, 512, 0, stream>>>(nebf, wbf, w, winv, labels, pl, tsv);
    }
    chunk_reduce_kernel<<<BATCH, 256, 0, stream>>>(pl, tsv, rl);
    final_kernel<<<1, 256, 0, stream>>>(rl, (float*)d_out);
}